// Round 9
// baseline (1341.115 us; speedup 1.0000x reference)
//
#include <hip/hip_runtime.h>
#include <hip/hip_bf16.h>
#include <hip/hip_cooperative_groups.h>

#define SEQ 256
#define IND 4096
#define HID 2048
#define NCLS 10
#define NBLK 256
#define COLS 8

// ---------------------------------------------------------------------------
// Kernel 1: xw = x @ W_hx (M=256,K=4096,N=2048 f32). 32x64 tile, BK=64,
// 256 blocks x 256 thr, 2x4 micro. (Known-good from round 8; LDS-BW-bound
// structure, left untouched this round.)
// ---------------------------------------------------------------------------
__global__ __launch_bounds__(256) void xw_gemm3(const float* __restrict__ A,
                                                const float* __restrict__ B,
                                                float* __restrict__ C) {
    __shared__ float As[32][68];
    __shared__ float Bs[64][64];
    const int bm = blockIdx.y * 32;
    const int bn = blockIdx.x * 64;
    const int tid = threadIdx.x;
    const int tx = tid & 15;
    const int ty = tid >> 4;

    float acc[2][4] = {};

    for (int k0 = 0; k0 < IND; k0 += 64) {
        {
            const int ar = tid >> 3;
            const int kq = (tid & 7) * 8;
            const float4 a0 = *reinterpret_cast<const float4*>(
                &A[(size_t)(bm + ar) * IND + k0 + kq]);
            const float4 a1 = *reinterpret_cast<const float4*>(
                &A[(size_t)(bm + ar) * IND + k0 + kq + 4]);
            *reinterpret_cast<float4*>(&As[ar][kq]) = a0;
            *reinterpret_cast<float4*>(&As[ar][kq + 4]) = a1;
        }
        {
            const int cq = (tid & 15) * 4;
            #pragma unroll
            for (int j = 0; j < 4; ++j) {
                const int kr = (tid >> 4) + j * 16;
                *reinterpret_cast<float4*>(&Bs[kr][cq]) =
                    *reinterpret_cast<const float4*>(
                        &B[(size_t)(k0 + kr) * HID + bn + cq]);
            }
        }
        __syncthreads();

        #pragma unroll
        for (int k4 = 0; k4 < 64; k4 += 4) {
            const float4 a0 = *reinterpret_cast<const float4*>(&As[ty * 2 + 0][k4]);
            const float4 a1 = *reinterpret_cast<const float4*>(&As[ty * 2 + 1][k4]);
            const float4 b0 = *reinterpret_cast<const float4*>(&Bs[k4 + 0][tx * 4]);
            const float4 b1 = *reinterpret_cast<const float4*>(&Bs[k4 + 1][tx * 4]);
            const float4 b2 = *reinterpret_cast<const float4*>(&Bs[k4 + 2][tx * 4]);
            const float4 b3 = *reinterpret_cast<const float4*>(&Bs[k4 + 3][tx * 4]);
            acc[0][0] += a0.x*b0.x + a0.y*b1.x + a0.z*b2.x + a0.w*b3.x;
            acc[0][1] += a0.x*b0.y + a0.y*b1.y + a0.z*b2.y + a0.w*b3.y;
            acc[0][2] += a0.x*b0.z + a0.y*b1.z + a0.z*b2.z + a0.w*b3.z;
            acc[0][3] += a0.x*b0.w + a0.y*b1.w + a0.z*b2.w + a0.w*b3.w;
            acc[1][0] += a1.x*b0.x + a1.y*b1.x + a1.z*b2.x + a1.w*b3.x;
            acc[1][1] += a1.x*b0.y + a1.y*b1.y + a1.z*b2.y + a1.w*b3.y;
            acc[1][2] += a1.x*b0.z + a1.y*b1.z + a1.z*b2.z + a1.w*b3.z;
            acc[1][3] += a1.x*b0.w + a1.y*b1.w + a1.z*b2.w + a1.w*b3.w;
        }
        __syncthreads();
    }

    #pragma unroll
    for (int i = 0; i < 2; ++i) {
        float4 cv = make_float4(acc[i][0], acc[i][1], acc[i][2], acc[i][3]);
        *reinterpret_cast<float4*>(
            &C[(size_t)(bm + ty * 2 + i) * HID + bn + tx * 4]) = cv;
    }
}

// f32 -> bf16 bits (round to nearest even)
__device__ __forceinline__ unsigned short f2bf(float f) {
    unsigned u = __float_as_uint(f);
    u += 0x7fffu + ((u >> 16) & 1u);
    return (unsigned short)(u >> 16);
}
__device__ __forceinline__ float bflo(unsigned u) { return __uint_as_float(u << 16); }
__device__ __forceinline__ float bfhi(unsigned u) { return __uint_as_float(u & 0xffff0000u); }

// ---------------------------------------------------------------------------
// Kernel 2: tagged-dataflow RNN, detect-and-accumulate fusion.
// 256 blocks x 256 thr; block b owns output rows [b*8, b*8+8).
// Thread tid polls EXACTLY the 8-word line published by block tid (one
// producer per thread, 64B). On tag match it immediately FMAs its 8 rows x
// 8 cols from bf16 W rows in LDS (swizzled b128 reads). Then: 3-stage
// 8-lane-group butterfly -> redT[t&1][32][9] -> ONE barrier -> wave-0
// reduce (4 LDS reads + shfl_xor 8/16/32) -> lanes 0..7 add xl+bias, tanh,
// publish 8 tagged words.
// Safety (2-deep parity, re-verified): overwrite of redT[p]/buf[p] at t+2
// requires detect(t+2) <= all published t+2 <= all consumed t+1 <= all
// published t+1 <= this block's redT[p]-read/publish at t (program order).
// Stale tags from prior graph replays carry identical deterministic values;
// 0xAA poison never matches a tag. v4-lesson kept: publish exactly 2048
// words/step, owner-side finish.
// ---------------------------------------------------------------------------
__global__ __launch_bounds__(256, 1) void rnn_v7(const float* __restrict__ W,
                                                 const float* __restrict__ xwg,
                                                 const float* __restrict__ b_h,
                                                 unsigned long long* __restrict__ buf) {
    const int b = blockIdx.x;
    const int tid = threadIdx.x;
    const int gbase = b * COLS;

    __shared__ unsigned short Wl[HID * COLS];   // 32 KiB bf16: [slot][kk][c]
    __shared__ float xl[SEQ * COLS];            // 8 KiB
    __shared__ float redT[2][32][9];            // parity x group x col (pad 9)

    // ---- stage W_hh row-blocks as bf16, k-swizzled (once)
    for (int rr = 0; rr < 8; ++rr) {
        const int r = rr * 256 + tid;
        const float4 w0 = *reinterpret_cast<const float4*>(&W[(size_t)r * HID + gbase]);
        const float4 w1 = *reinterpret_cast<const float4*>(&W[(size_t)r * HID + gbase + 4]);
        uint4 pk;
        pk.x = (unsigned)f2bf(w0.x) | ((unsigned)f2bf(w0.y) << 16);
        pk.y = (unsigned)f2bf(w0.z) | ((unsigned)f2bf(w0.w) << 16);
        pk.z = (unsigned)f2bf(w1.x) | ((unsigned)f2bf(w1.y) << 16);
        pk.w = (unsigned)f2bf(w1.z) | ((unsigned)f2bf(w1.w) << 16);
        const int slot = r >> 3;
        const int kk = (r & 7) ^ ((slot >> 2) & 7);
        *reinterpret_cast<uint4*>(&Wl[(slot * 8 + kk) * 8]) = pk;
    }
    // ---- stage xl strip (once)
    for (int ii = 0; ii < 8; ++ii) {
        const int idx = ii * 256 + tid;
        xl[idx] = xwg[(size_t)(idx >> 3) * HID + gbase + (idx & 7)];
    }
    const float bias = (tid < COLS) ? b_h[gbase + tid] : 0.0f;
    __syncthreads();

    const int myswz = (tid >> 2) & 7;
    const unsigned long long* mybase = buf + (size_t)tid * 8;

    for (int t = 0; t < SEQ; ++t) {
        float part[8] = {0.f, 0.f, 0.f, 0.f, 0.f, 0.f, 0.f, 0.f};

        if (t > 0) {
            const unsigned long long* bb = mybase + (size_t)(t & 1) * HID;
            const unsigned tg = (unsigned)t;
            unsigned long long w[8];
            for (;;) {
                #pragma unroll
                for (int k = 0; k < 8; ++k)
                    w[k] = __hip_atomic_load(&bb[k], __ATOMIC_RELAXED,
                                             __HIP_MEMORY_SCOPE_AGENT);
                bool ok = true;
                #pragma unroll
                for (int k = 0; k < 8; ++k)
                    ok &= ((unsigned)(w[k] >> 32) == tg);
                if (ok) break;
            }
            // detect-and-accumulate: 8 rows x 8 cols, one b128 W-read per row
            #pragma unroll
            for (int k = 0; k < 8; ++k) {
                const float vk = __uint_as_float((unsigned)w[k]);
                const int kk = k ^ myswz;
                const uint4 wq = *reinterpret_cast<const uint4*>(
                    &Wl[(tid * 8 + kk) * 8]);
                part[0] += vk * bflo(wq.x); part[1] += vk * bfhi(wq.x);
                part[2] += vk * bflo(wq.y); part[3] += vk * bfhi(wq.y);
                part[4] += vk * bflo(wq.z); part[5] += vk * bfhi(wq.z);
                part[6] += vk * bflo(wq.w); part[7] += vk * bfhi(wq.w);
            }
        }

        // ---- 3-stage butterfly within 8-lane groups (all cols reduced)
        #pragma unroll
        for (int s = 1; s <= 4; s <<= 1) {
            #pragma unroll
            for (int c = 0; c < 8; ++c)
                part[c] += __shfl_xor(part[c], s, 64);
        }
        // lane writes its own col (static-index select, no scratch)
        float myv = part[0];
        #pragma unroll
        for (int c = 1; c < 8; ++c) myv = ((tid & 7) == c) ? part[c] : myv;
        redT[t & 1][tid >> 3][tid & 7] = myv;
        __syncthreads();

        // ---- wave-0 reduce + finish + publish
        if (tid < 64) {
            const int c = tid & 7, h = tid >> 3;
            const float* rp = &redT[t & 1][0][0];
            float s = rp[(h * 4 + 0) * 9 + c] + rp[(h * 4 + 1) * 9 + c]
                    + rp[(h * 4 + 2) * 9 + c] + rp[(h * 4 + 3) * 9 + c];
            s += __shfl_xor(s, 8, 64);
            s += __shfl_xor(s, 16, 64);
            s += __shfl_xor(s, 32, 64);
            if (tid < 8) {
                const float hh = tanhf(s + xl[t * COLS + tid] + bias);
                const unsigned long long pk =
                    ((unsigned long long)(unsigned)(t + 1) << 32) |
                    (unsigned long long)__float_as_uint(hh);
                __hip_atomic_store(&buf[(size_t)((t + 1) & 1) * HID + gbase + tid],
                                   pk, __ATOMIC_RELAXED, __HIP_MEMORY_SCOPE_AGENT);
            }
        }
    }
}

// ---------------------------------------------------------------------------
// Kernel 3: out = softmax(2048 * (v @ W_ph + b_p)); v = tag-256 values in
// buf parity 0 (stream-ordered after rnn_v7 -> plain reads).
// ---------------------------------------------------------------------------
__global__ __launch_bounds__(256) void final_v3(const unsigned long long* __restrict__ buf,
                                                const float* __restrict__ W_ph,
                                                const float* __restrict__ b_p,
                                                float* __restrict__ out) {
    __shared__ float red[256][NCLS];
    const int tid = threadIdx.x;
    float acc[NCLS] = {};
    for (int k = 0; k < 8; ++k) {
        const int r = k * 256 + tid;
        const float v = __uint_as_float((unsigned)buf[r]);   // parity 0
        #pragma unroll
        for (int c = 0; c < NCLS; ++c)
            acc[c] += v * W_ph[(size_t)r * NCLS + c];
    }
    #pragma unroll
    for (int c = 0; c < NCLS; ++c) red[tid][c] = acc[c];
    __syncthreads();
    for (int sft = 128; sft > 0; sft >>= 1) {
        if (tid < sft) {
            #pragma unroll
            for (int c = 0; c < NCLS; ++c)
                red[tid][c] += red[tid + sft][c];
        }
        __syncthreads();
    }
    if (tid == 0) {
        float logits[NCLS];
        float m = -1e30f;
        #pragma unroll
        for (int c = 0; c < NCLS; ++c) {
            logits[c] = (float)HID * (red[0][c] + b_p[c]);
            m = fmaxf(m, logits[c]);
        }
        float den = 0.0f, e[NCLS];
        #pragma unroll
        for (int c = 0; c < NCLS; ++c) {
            e[c] = expf(logits[c] - m);
            den += e[c];
        }
        #pragma unroll
        for (int c = 0; c < NCLS; ++c) out[c] = e[c] / den;
    }
}

// ---------------------------------------------------------------------------
extern "C" void kernel_launch(void* const* d_in, const int* in_sizes, int n_in,
                              void* d_out, int out_size, void* d_ws, size_t ws_size,
                              hipStream_t stream) {
    const float* x    = (const float*)d_in[0];
    const float* W_hx = (const float*)d_in[1];
    const float* W_hh = (const float*)d_in[2];
    const float* W_ph = (const float*)d_in[3];
    const float* b_h  = (const float*)d_in[4];
    const float* b_p  = (const float*)d_in[5];
    float* out = (float*)d_out;

    float* xw               = (float*)d_ws;                                  // 2 MB
    unsigned long long* buf = (unsigned long long*)(xw + (size_t)SEQ * HID); // 32 KB

    // 1) xw = x @ W_hx
    dim3 g1(HID / 64, SEQ / 32);
    xw_gemm3<<<g1, 256, 0, stream>>>(x, W_hx, xw);

    // 2) recurrent steps (cooperative for co-residency; dataflow sync)
    {
        const float* whh_a = W_hh;
        const float* xw_a  = xw;
        const float* bh_a  = b_h;
        unsigned long long* buf_a = buf;
        void* args[] = {(void*)&whh_a, (void*)&xw_a, (void*)&bh_a, (void*)&buf_a};
        hipLaunchCooperativeKernel((const void*)rnn_v7, dim3(NBLK), dim3(256),
                                   args, 0, stream);
    }

    // 3) projection + softmax
    final_v3<<<1, 256, 0, stream>>>(buf, W_ph, b_p, out);
}

// Round 10
// 1072.720 us; speedup vs baseline: 1.2502x; 1.2502x over previous
//
#include <hip/hip_runtime.h>
#include <hip/hip_bf16.h>
#include <hip/hip_cooperative_groups.h>

#define SEQ 256
#define IND 4096
#define HID 2048
#define NCLS 10
#define NBLK 256
#define COLS 8
#define BSTRIDE 512                 // u64 per block granule (4 KB)
#define POFF (NBLK * BSTRIDE)       // u64 per parity (1 MB)

// ---------------------------------------------------------------------------
// Kernel 1: xw = x @ W_hx (M=256,K=4096,N=2048 f32). Known-good, untouched.
// ---------------------------------------------------------------------------
__global__ __launch_bounds__(256) void xw_gemm3(const float* __restrict__ A,
                                                const float* __restrict__ B,
                                                float* __restrict__ C) {
    __shared__ float As[32][68];
    __shared__ float Bs[64][64];
    const int bm = blockIdx.y * 32;
    const int bn = blockIdx.x * 64;
    const int tid = threadIdx.x;
    const int tx = tid & 15;
    const int ty = tid >> 4;

    float acc[2][4] = {};

    for (int k0 = 0; k0 < IND; k0 += 64) {
        {
            const int ar = tid >> 3;
            const int kq = (tid & 7) * 8;
            const float4 a0 = *reinterpret_cast<const float4*>(
                &A[(size_t)(bm + ar) * IND + k0 + kq]);
            const float4 a1 = *reinterpret_cast<const float4*>(
                &A[(size_t)(bm + ar) * IND + k0 + kq + 4]);
            *reinterpret_cast<float4*>(&As[ar][kq]) = a0;
            *reinterpret_cast<float4*>(&As[ar][kq + 4]) = a1;
        }
        {
            const int cq = (tid & 15) * 4;
            #pragma unroll
            for (int j = 0; j < 4; ++j) {
                const int kr = (tid >> 4) + j * 16;
                *reinterpret_cast<float4*>(&Bs[kr][cq]) =
                    *reinterpret_cast<const float4*>(
                        &B[(size_t)(k0 + kr) * HID + bn + cq]);
            }
        }
        __syncthreads();

        #pragma unroll
        for (int k4 = 0; k4 < 64; k4 += 4) {
            const float4 a0 = *reinterpret_cast<const float4*>(&As[ty * 2 + 0][k4]);
            const float4 a1 = *reinterpret_cast<const float4*>(&As[ty * 2 + 1][k4]);
            const float4 b0 = *reinterpret_cast<const float4*>(&Bs[k4 + 0][tx * 4]);
            const float4 b1 = *reinterpret_cast<const float4*>(&Bs[k4 + 1][tx * 4]);
            const float4 b2 = *reinterpret_cast<const float4*>(&Bs[k4 + 2][tx * 4]);
            const float4 b3 = *reinterpret_cast<const float4*>(&Bs[k4 + 3][tx * 4]);
            acc[0][0] += a0.x*b0.x + a0.y*b1.x + a0.z*b2.x + a0.w*b3.x;
            acc[0][1] += a0.x*b0.y + a0.y*b1.y + a0.z*b2.y + a0.w*b3.y;
            acc[0][2] += a0.x*b0.z + a0.y*b1.z + a0.z*b2.z + a0.w*b3.z;
            acc[0][3] += a0.x*b0.w + a0.y*b1.w + a0.z*b2.w + a0.w*b3.w;
            acc[1][0] += a1.x*b0.x + a1.y*b1.x + a1.z*b2.x + a1.w*b3.x;
            acc[1][1] += a1.x*b0.y + a1.y*b1.y + a1.z*b2.y + a1.w*b3.y;
            acc[1][2] += a1.x*b0.z + a1.y*b1.z + a1.z*b2.z + a1.w*b3.z;
            acc[1][3] += a1.x*b0.w + a1.y*b1.w + a1.z*b2.w + a1.w*b3.w;
        }
        __syncthreads();
    }

    #pragma unroll
    for (int i = 0; i < 2; ++i) {
        float4 cv = make_float4(acc[i][0], acc[i][1], acc[i][2], acc[i][3]);
        *reinterpret_cast<float4*>(
            &C[(size_t)(bm + ty * 2 + i) * HID + bn + tx * 4]) = cv;
    }
}

// ---------------------------------------------------------------------------
// Kernel 2: tagged-dataflow RNN (mega/v6 wave-autonomous structure, f32 W,
// barrier finish) with GRANULE-SPREAD publish lines: block b's 8 tagged
// words live at buf[parity*POFF + b*512 + c] -> each block's line is a
// distinct 4KB granule, spreading the polled hot set over all MALL slices
// (A/B vs the packed 16KB layout that may serialize on a few slices).
// Wave wid owns rows [wid*512, wid*512+512): it polls exactly those 64
// lines, writes its own XOR-swizzled v2 quarter, and runs its GEMV without
// a block barrier (reads only its own quarter). One barrier/step before
// the 8-lane owner finish. 2-deep parity overwrite safety: publish(t+3)
// requires all blocks' detect(t+1) complete (two-hop gating chain), so a
// parity slot is never overwritten before all its readers are done.
// Stale tags from prior graph replays carry identical deterministic
// values; the 0xAA poison pattern never matches a tag.
// ---------------------------------------------------------------------------
__global__ __launch_bounds__(256, 1) void rnn_v8(const float* __restrict__ W,
                                                 const float* __restrict__ xwg,
                                                 const float* __restrict__ b_h,
                                                 unsigned long long* __restrict__ buf) {
    const int b = blockIdx.x;
    const int tid = threadIdx.x;
    const int gbase = b * COLS;
    const int lane = tid & 63;
    const int wid = tid >> 6;
    const int sl = lane >> 3;
    const int col = lane & 7;
    const int seg = wid * 8 + sl;

    __shared__ float Wf[16 * 32 * COLS * 4];   // 64 KiB f32 [i][seg][col][e]
    __shared__ float v2[2048];                 // 8 KiB, XOR-swizzled
    __shared__ float xl[SEQ * COLS];           // 8 KiB
    __shared__ float red[2][4][COLS];

    // ---- stage W_hh column slice (once)
    for (int chunk = 0; chunk < 16; ++chunk) {
        const int r = chunk * 128 + (tid >> 1);
        const int c4 = (tid & 1) * 4;
        const float4 w4 = *reinterpret_cast<const float4*>(
            &W[(size_t)r * HID + gbase + c4]);
        const int i = (r >> 2) & 15, sg = r >> 6, e = r & 3;
        const float vls[4] = {w4.x, w4.y, w4.z, w4.w};
        #pragma unroll
        for (int j = 0; j < 4; ++j)
            Wf[(((i * 32 + sg) * COLS) + c4 + j) * 4 + e] = vls[j];
    }
    // ---- stage xl strip (once)
    for (int ii = 0; ii < 8; ++ii) {
        const int idx = ii * 256 + tid;
        xl[idx] = xwg[(size_t)(idx >> 3) * HID + gbase + (idx & 7)];
    }
    const float bias = (tid < COLS) ? b_h[gbase + tid] : 0.0f;
    // zero my wave's v2 quarter (content 0 -> swizzle irrelevant)
    #pragma unroll
    for (int k = 0; k < 8; ++k) v2[wid * 512 + k * 64 + lane] = 0.0f;
    __syncthreads();

    for (int t = 0; t < SEQ; ++t) {
        // ---- wave-autonomous detect of tag t over own 512 rows
        if (t > 0) {
            const unsigned long long* bb = buf + (size_t)(t & 1) * POFF;
            const unsigned tg = (unsigned)t;
            unsigned long long w[8];
            unsigned got = 0;
            #pragma unroll
            for (int k = 0; k < 8; ++k) {
                const int r = wid * 512 + k * 64 + lane;
                w[k] = __hip_atomic_load(&bb[(size_t)(r >> 3) * BSTRIDE + (r & 7)],
                                         __ATOMIC_RELAXED, __HIP_MEMORY_SCOPE_AGENT);
            }
            for (;;) {
                #pragma unroll
                for (int k = 0; k < 8; ++k) {
                    if (!(got & (1u << k)) && (unsigned)(w[k] >> 32) == tg) {
                        const int r = wid * 512 + k * 64 + lane;
                        const int i = (r >> 2) & 15, sg = r >> 6, e = r & 3;
                        const int bw = (i * 128 + sg * 4) ^ ((i & 7) << 2);
                        v2[bw + e] = __uint_as_float((unsigned)w[k]);
                        got |= (1u << k);
                    }
                }
                if (got == 0xFFu) break;
                #pragma unroll
                for (int k = 0; k < 8; ++k) {
                    if (!(got & (1u << k))) {
                        const int r = wid * 512 + k * 64 + lane;
                        w[k] = __hip_atomic_load(
                            &bb[(size_t)(r >> 3) * BSTRIDE + (r & 7)],
                            __ATOMIC_RELAXED, __HIP_MEMORY_SCOPE_AGENT);
                    }
                }
            }
        }
        // (no barrier: GEMV reads only this wave's v2 quarter)

        // ---- GEMV over own 64-row chunk (seg)
        float acc = 0.0f;
        #pragma unroll
        for (int i = 0; i < 16; ++i) {
            const float4 wq = *reinterpret_cast<const float4*>(
                &Wf[((i * 32 + seg) * COLS + col) * 4]);
            const int vb = (i * 128 + seg * 4) ^ ((i & 7) << 2);
            const float4 vq = *reinterpret_cast<const float4*>(&v2[vb]);
            acc += wq.x * vq.x + wq.y * vq.y + wq.z * vq.z + wq.w * vq.w;
        }
        acc += __shfl_xor(acc, 8, 64);
        acc += __shfl_xor(acc, 16, 64);
        acc += __shfl_xor(acc, 32, 64);

        // ---- barrier + 8-lane owner finish
        const int p = t & 1;
        if (lane < COLS) red[p][wid][lane] = acc;
        __syncthreads();

        if (tid < COLS) {
            const float s = xl[t * COLS + tid] + bias
                          + red[p][0][tid] + red[p][1][tid]
                          + red[p][2][tid] + red[p][3][tid];
            const float h = tanhf(s);
            const unsigned long long pk =
                ((unsigned long long)(unsigned)(t + 1) << 32) |
                (unsigned long long)__float_as_uint(h);
            __hip_atomic_store(&buf[(size_t)((t + 1) & 1) * POFF
                                    + (size_t)b * BSTRIDE + tid],
                               pk, __ATOMIC_RELAXED, __HIP_MEMORY_SCOPE_AGENT);
        }
    }
}

// ---------------------------------------------------------------------------
// Kernel 3: out = softmax(2048 * (v @ W_ph + b_p)); v = tag-256 values at
// parity 0 of the strided buf (stream-ordered after rnn_v8 -> plain reads).
// ---------------------------------------------------------------------------
__global__ __launch_bounds__(256) void final_v4(const unsigned long long* __restrict__ buf,
                                                const float* __restrict__ W_ph,
                                                const float* __restrict__ b_p,
                                                float* __restrict__ out) {
    __shared__ float red[256][NCLS];
    const int tid = threadIdx.x;
    float acc[NCLS] = {};
    for (int k = 0; k < 8; ++k) {
        const int r = k * 256 + tid;
        const float v = __uint_as_float(
            (unsigned)buf[(size_t)(r >> 3) * BSTRIDE + (r & 7)]);   // parity 0
        #pragma unroll
        for (int c = 0; c < NCLS; ++c)
            acc[c] += v * W_ph[(size_t)r * NCLS + c];
    }
    #pragma unroll
    for (int c = 0; c < NCLS; ++c) red[tid][c] = acc[c];
    __syncthreads();
    for (int sft = 128; sft > 0; sft >>= 1) {
        if (tid < sft) {
            #pragma unroll
            for (int c = 0; c < NCLS; ++c)
                red[tid][c] += red[tid + sft][c];
        }
        __syncthreads();
    }
    if (tid == 0) {
        float logits[NCLS];
        float m = -1e30f;
        #pragma unroll
        for (int c = 0; c < NCLS; ++c) {
            logits[c] = (float)HID * (red[0][c] + b_p[c]);
            m = fmaxf(m, logits[c]);
        }
        float den = 0.0f, e[NCLS];
        #pragma unroll
        for (int c = 0; c < NCLS; ++c) {
            e[c] = expf(logits[c] - m);
            den += e[c];
        }
        #pragma unroll
        for (int c = 0; c < NCLS; ++c) out[c] = e[c] / den;
    }
}

// ---------------------------------------------------------------------------
extern "C" void kernel_launch(void* const* d_in, const int* in_sizes, int n_in,
                              void* d_out, int out_size, void* d_ws, size_t ws_size,
                              hipStream_t stream) {
    const float* x    = (const float*)d_in[0];
    const float* W_hx = (const float*)d_in[1];
    const float* W_hh = (const float*)d_in[2];
    const float* W_ph = (const float*)d_in[3];
    const float* b_h  = (const float*)d_in[4];
    const float* b_p  = (const float*)d_in[5];
    float* out = (float*)d_out;

    float* xw               = (float*)d_ws;                                  // 2 MB
    unsigned long long* buf = (unsigned long long*)(xw + (size_t)SEQ * HID); // 2 MB

    // 1) xw = x @ W_hx
    dim3 g1(HID / 64, SEQ / 32);
    xw_gemm3<<<g1, 256, 0, stream>>>(x, W_hx, xw);

    // 2) recurrent steps (cooperative for co-residency; dataflow sync)
    {
        const float* whh_a = W_hh;
        const float* xw_a  = xw;
        const float* bh_a  = b_h;
        unsigned long long* buf_a = buf;
        void* args[] = {(void*)&whh_a, (void*)&xw_a, (void*)&bh_a, (void*)&buf_a};
        hipLaunchCooperativeKernel((const void*)rnn_v8, dim3(NBLK), dim3(256),
                                   args, 0, stream);
    }

    // 3) projection + softmax
    final_v4<<<1, 256, 0, stream>>>(buf, W_ph, b_p, out);
}